// Round 1
// baseline (5149.710 us; speedup 1.0000x reference)
//
#include <hip/hip_runtime.h>
#include <hip/hip_bf16.h>

typedef __bf16 bf16;
typedef bf16 bf16x8 __attribute__((ext_vector_type(8)));
typedef float f32x4 __attribute__((ext_vector_type(4)));

__device__ __forceinline__ void glds16(const void* g, void* l) {
    __builtin_amdgcn_global_load_lds(
        (const __attribute__((address_space(1))) void*)g,
        (__attribute__((address_space(3))) void*)l, 16, 0, 0);
}

__device__ __forceinline__ float sigm(float x) { return 1.0f / (1.0f + __expf(-x)); }
__device__ __forceinline__ float tanh_f(float x) { return 2.0f / (1.0f + __expf(-2.0f * x)) - 1.0f; }

// ---------------------------------------------------------------------------
// fp32 -> bf16 conversion of x + 11 matrices into one packed ws area.
// ---------------------------------------------------------------------------
struct Cvt11 { const float* src[11]; unsigned gcnt[11]; };  // gcnt = elems/8

__global__ __launch_bounds__(256) void cvt_all(Cvt11 a, bf16* __restrict__ dst,
                                               unsigned total_g) {
    unsigned g = blockIdx.x * 256 + threadIdx.x;
    if (g >= total_g) return;
    unsigned s = 0, base = 0;
    while (g >= base + a.gcnt[s]) { base += a.gcnt[s]; ++s; }
    const float* sp = a.src[s] + (size_t)(g - base) * 8;
    float4 v0 = ((const float4*)sp)[0];
    float4 v1 = ((const float4*)sp)[1];
    bf16x8 o;
    o[0] = (bf16)v0.x; o[1] = (bf16)v0.y; o[2] = (bf16)v0.z; o[3] = (bf16)v0.w;
    o[4] = (bf16)v1.x; o[5] = (bf16)v1.y; o[6] = (bf16)v1.z; o[7] = (bf16)v1.w;
    *(bf16x8*)(dst + (size_t)g * 8) = o;
}

// Pack Wcomb[2048,544] = Whh[2048,512] || Wih[2048,16] || zeros[16], bf16.
__global__ __launch_bounds__(128) void pack_w(const float* __restrict__ Whh,
                                              const float* __restrict__ Wih,
                                              bf16* __restrict__ Wc) {
    int row = blockIdx.x, seg = threadIdx.x;
    if (seg >= 68) return;
    bf16x8 o = {};
    if (seg < 64) {
        const float* sp = Whh + (size_t)row * 512 + seg * 8;
        float4 v0 = ((const float4*)sp)[0];
        float4 v1 = ((const float4*)sp)[1];
        o[0]=(bf16)v0.x; o[1]=(bf16)v0.y; o[2]=(bf16)v0.z; o[3]=(bf16)v0.w;
        o[4]=(bf16)v1.x; o[5]=(bf16)v1.y; o[6]=(bf16)v1.z; o[7]=(bf16)v1.w;
    } else if (seg < 66) {
        const float* sp = Wih + (size_t)row * 16 + (seg - 64) * 8;
        float4 v0 = ((const float4*)sp)[0];
        float4 v1 = ((const float4*)sp)[1];
        o[0]=(bf16)v0.x; o[1]=(bf16)v0.y; o[2]=(bf16)v0.z; o[3]=(bf16)v0.w;
        o[4]=(bf16)v1.x; o[5]=(bf16)v1.y; o[6]=(bf16)v1.z; o[7]=(bf16)v1.w;
    }
    *(bf16x8*)(Wc + (size_t)row * 544 + seg * 8) = o;
}

// Zero pad cols 528..543 of both h buffers + zero the grid-barrier words.
__global__ __launch_bounds__(256) void zero_pad(bf16* __restrict__ h0,
                                                bf16* __restrict__ h1,
                                                unsigned* __restrict__ bvars) {
    int g = blockIdx.x * 256 + threadIdx.x;  // 4096*2*2 = 16384
    if (g < 2) bvars[g] = 0u;                // graph-replay-safe barrier init
    int row = g >> 2, b = (g >> 1) & 1, half = g & 1;
    bf16* p = (b ? h1 : h0) + (size_t)row * 544 + 528 + half * 8;
    *(bf16x8*)p = (bf16x8){};
}

// ---------------------------------------------------------------------------
// GEMM: C[M,N](ldc) = act(A[M,K] @ W[N,K]^T + bias).  BM=64, BN=128, BK=32.
// ---------------------------------------------------------------------------
template <int ACT, typename OutT>
__global__ __launch_bounds__(256) void gemm_bt(
    const bf16* __restrict__ A, const bf16* __restrict__ W,
    const float* __restrict__ bias, OutT* __restrict__ C,
    int M, int N, int K, int ldc)
{
    __shared__ __attribute__((aligned(16))) bf16 sA[64 * 32];   // 4 KB
    __shared__ __attribute__((aligned(16))) bf16 sB[128 * 32];  // 8 KB
    const int t = threadIdx.x;
    const int lane = t & 63, w = t >> 6;
    const int wm = w >> 1, wn = w & 1;
    const int quad = lane >> 4, l16 = lane & 15;
    const int m0 = blockIdx.y * 64, n0 = blockIdx.x * 128;

    f32x4 acc[2][4] = {};

    const int nk = K >> 5;
    for (int kc = 0; kc < nk; ++kc) {
        const int k0 = kc << 5;
        if (kc) __syncthreads();
        {   // A: 64x32 = 4 KB
            int row = t >> 2, kof = (t & 3) << 3;
            glds16(A + (size_t)(m0 + row) * K + k0 + kof, (char*)sA + (w << 10));
        }
        for (int i = 0; i < 2; ++i) {  // B: 128x32 = 8 KB
            int gi = (i << 8) + t;
            int row = gi >> 2, kof = (gi & 3) << 3;
            glds16(W + (size_t)(n0 + row) * K + k0 + kof,
                   (char*)sB + (i << 12) + (w << 10));
        }
        __syncthreads();
        bf16x8 af[2], bfr[4];
        for (int mi = 0; mi < 2; ++mi)
            af[mi] = *(const bf16x8*)(sA + ((wm * 32 + mi * 16 + l16) * 32 + quad * 8));
        for (int ni = 0; ni < 4; ++ni)
            bfr[ni] = *(const bf16x8*)(sB + ((wn * 64 + ni * 16 + l16) * 32 + quad * 8));
        for (int mi = 0; mi < 2; ++mi)
            for (int ni = 0; ni < 4; ++ni)
                acc[mi][ni] = __builtin_amdgcn_mfma_f32_16x16x32_bf16(
                    af[mi], bfr[ni], acc[mi][ni], 0, 0, 0);
    }
    for (int mi = 0; mi < 2; ++mi) {
        for (int ni = 0; ni < 4; ++ni) {
            int gn = n0 + wn * 64 + ni * 16 + l16;
            float bv = bias[gn];
            for (int r = 0; r < 4; ++r) {
                int gm = m0 + wm * 32 + mi * 16 + quad * 4 + r;
                float v = acc[mi][ni][r] + bv;
                if (ACT) v = v >= 0.f ? v : 0.2f * v;
                C[(size_t)gm * ldc + gn] = (OutT)v;
            }
        }
    }
}

// ---------------------------------------------------------------------------
// MFMA head (used once, for x0): p = A[:,0:512](lda) @ Wp[16,512]^T + b.
// ---------------------------------------------------------------------------
__global__ __launch_bounds__(256) void head_mfma(
    const bf16* __restrict__ A, int lda,
    const bf16* __restrict__ Wp16,
    const float* __restrict__ bias,
    bf16* __restrict__ xt_dst, int ldx,
    float* __restrict__ outp, int ldo)
{
    const int t = threadIdx.x;
    const int lane = t & 63, w = t >> 6;
    const int quad = lane >> 4, l16 = lane & 15;
    const int r0 = blockIdx.x * 64 + w * 16;
    f32x4 acc = {};
    for (int kk = 0; kk < 16; ++kk) {
        bf16x8 a = *(const bf16x8*)(A + (size_t)(r0 + l16) * lda + kk * 32 + quad * 8);
        bf16x8 b = *(const bf16x8*)(Wp16 + (size_t)l16 * 512 + kk * 32 + quad * 8);
        acc = __builtin_amdgcn_mfma_f32_16x16x32_bf16(a, b, acc, 0, 0, 0);
    }
    const int n = l16;
    const float bv = bias[n];
    for (int r = 0; r < 4; ++r) {
        float p = acc[r] + bv;
        float vmax = (n == 15) ? -3.0e38f : p;
        for (int m = 1; m < 16; m <<= 1) vmax = fmaxf(vmax, __shfl_xor(vmax, m));
        float e = (n == 15) ? 0.f : __expf(p - vmax);
        float s = e;
        for (int m = 1; m < 16; m <<= 1) s += __shfl_xor(s, m);
        float res = (n == 15) ? sigm(p) : e / s;
        int gr = r0 + quad * 4 + r;
        xt_dst[(size_t)gr * ldx + n] = (bf16)res;
        if (outp) outp[(size_t)gr * ldo + n] = res;
    }
}

// ---------------------------------------------------------------------------
// Grid-wide generation barrier (all blocks guaranteed resident: 512 blocks,
// __launch_bounds__(256,4) => <=128 VGPR => 4 blocks/CU allowed, need 2).
// __threadfence(): release = buffer_wbl2, acquire = buffer_inv (agent scope)
// -> same coherence cost a kernel boundary already paid.
// ---------------------------------------------------------------------------
#define NBLK 512u
__device__ __forceinline__ void gsync(unsigned* cnt, unsigned* gen) {
    __syncthreads();
    if (threadIdx.x == 0) {
        __threadfence();  // release: make h/ppart stores visible device-wide
        unsigned g = __hip_atomic_load(gen, __ATOMIC_RELAXED, __HIP_MEMORY_SCOPE_AGENT);
        unsigned a = __hip_atomic_fetch_add(cnt, 1u, __ATOMIC_RELAXED,
                                            __HIP_MEMORY_SCOPE_AGENT);
        if (a == NBLK - 1u) {
            __hip_atomic_store(cnt, 0u, __ATOMIC_RELAXED, __HIP_MEMORY_SCOPE_AGENT);
            __hip_atomic_fetch_add(gen, 1u, __ATOMIC_RELEASE,
                                   __HIP_MEMORY_SCOPE_AGENT);
        } else {
            while (__hip_atomic_load(gen, __ATOMIC_RELAXED,
                                     __HIP_MEMORY_SCOPE_AGENT) == g) {
                __builtin_amdgcn_s_sleep(8);
            }
        }
        __threadfence();  // acquire: invalidate stale L1/L2 before next phase
    }
    __syncthreads();
}

// ---------------------------------------------------------------------------
// Persistent fused LSTM loop: 32 steps, head fused, c resident in LDS.
// Block (mb,jb): rows mb*128..+127, units jb*32..+31 (all 4 gates).
// Per step: 17x BK=32 MFMA phases -> epilogue (gates, c in LDS, h write,
// hn tile -> sA) -> 2 MFMA head partials -> gsync -> 128-thread softmax
// (16-way partial reduce) writes xt into h buffer + out[t] -> gsync.
// ---------------------------------------------------------------------------
__global__ __launch_bounds__(256, 4) void lstm_loop(
    const bf16* __restrict__ Wc,    // [2048,544]
    const bf16* __restrict__ Wp16,  // [16,512]
    const float* __restrict__ bih, const float* __restrict__ bhh,
    const float* __restrict__ bp,
    const float* __restrict__ cb,   // [4096,512] fp32 (c0; read once)
    bf16* __restrict__ h0, bf16* __restrict__ h1,   // [4096,544]
    float* __restrict__ ppart,      // [16,4096,16] f32 (aliases dead bufB)
    float* __restrict__ outp,       // [4096, 512]  (= [B, T*16])
    unsigned* __restrict__ bvars)
{
    __shared__ __attribute__((aligned(16))) bf16 sA[128 * 32];  // 8 KB (also hn bounce)
    __shared__ __attribute__((aligned(16))) bf16 sB[128 * 32];  // 8 KB
    __shared__ float sC[128 * 32];                              // 16 KB resident c
    const int t = threadIdx.x;
    const int lane = t & 63, w = t >> 6;
    const int wm = w >> 1, wn = w & 1;
    const int quad = lane >> 4, l16 = lane & 15;
    const int bid = blockIdx.x;
    const int jb = bid & 15, mb = bid >> 4;
    const int m0 = mb * 128, j0 = jb * 32;
    const int j = j0 + wn * 16 + l16;

    // init: c slice -> LDS; hoist biases + Wp fragment (constant across steps)
    for (int mi = 0; mi < 4; ++mi)
        for (int r = 0; r < 4; ++r) {
            int lr = wm * 64 + mi * 16 + quad * 4 + r;
            sC[lr * 32 + wn * 16 + l16] = cb[(size_t)(m0 + lr) * 512 + j];
        }
    float bsum[4];
    for (int g = 0; g < 4; ++g) bsum[g] = bih[(g << 9) + j] + bhh[(g << 9) + j];
    const bf16x8 wpf = *(const bf16x8*)(Wp16 + (size_t)l16 * 512 + j0 + quad * 8);
    const float pb = bp[t & 15];

    for (int st = 0; st < 32; ++st) {
        const bf16* hin = (st & 1) ? h1 : h0;
        bf16* hout = (st & 1) ? h0 : h1;

        f32x4 acc[4][4] = {};  // [mi][gate]
        for (int kc = 0; kc < 17; ++kc) {
            const int k0 = kc << 5;
            if (kc) __syncthreads();
            for (int i = 0; i < 2; ++i) {  // A tile: 128 rows of h (stride 544)
                int gi = (i << 8) + t;
                int row = gi >> 2, kof = (gi & 3) << 3;
                glds16(hin + (size_t)(m0 + row) * 544 + k0 + kof,
                       (char*)sA + (i << 12) + (w << 10));
            }
            for (int i = 0; i < 2; ++i) {  // B tile: 4 gates x 32 units
                int gi = (i << 8) + t;
                int row = gi >> 2, kof = (gi & 3) << 3;
                int wr = ((row >> 5) << 9) + j0 + (row & 31);
                glds16(Wc + (size_t)wr * 544 + k0 + kof,
                       (char*)sB + (i << 12) + (w << 10));
            }
            __syncthreads();
            bf16x8 af[4], bfr[4];
            for (int mi = 0; mi < 4; ++mi)
                af[mi] = *(const bf16x8*)(sA + ((wm * 64 + mi * 16 + l16) * 32 + quad * 8));
            for (int g = 0; g < 4; ++g)
                bfr[g] = *(const bf16x8*)(sB + ((g * 32 + wn * 16 + l16) * 32 + quad * 8));
            for (int mi = 0; mi < 4; ++mi)
                for (int g = 0; g < 4; ++g)
                    acc[mi][g] = __builtin_amdgcn_mfma_f32_16x16x32_bf16(
                        af[mi], bfr[g], acc[mi][g], 0, 0, 0);
        }
        __syncthreads();  // all waves done reading sA/sB before sA reuse

        // epilogue: gates, c update (LDS-resident), h write, hn tile -> sA
        for (int mi = 0; mi < 4; ++mi) {
            for (int r = 0; r < 4; ++r) {
                int lr = wm * 64 + mi * 16 + quad * 4 + r;
                int gm = m0 + lr;
                float i_ = sigm(acc[mi][0][r] + bsum[0]);
                float f_ = sigm(acc[mi][1][r] + bsum[1]);
                float g_ = tanh_f(acc[mi][2][r] + bsum[2]);
                float o_ = sigm(acc[mi][3][r] + bsum[3]);
                int ci = lr * 32 + wn * 16 + l16;
                float cn = f_ * sC[ci] + i_ * g_;
                sC[ci] = cn;
                float hv = o_ * tanh_f(cn);
                bf16 hb = (bf16)hv;
                hout[(size_t)gm * 544 + j] = hb;
                sA[ci] = hb;  // sH tile, same [128][32] layout
            }
        }
        __syncthreads();

        // head partial: p_part[rows w*32..+31, 16] = hn_tile @ Wp[:, j0:j0+32]^T
        {
            const int r0 = w * 32;
            bf16x8 a0 = *(const bf16x8*)(sA + (r0 + l16) * 32 + quad * 8);
            bf16x8 a1 = *(const bf16x8*)(sA + (r0 + 16 + l16) * 32 + quad * 8);
            f32x4 p0 = {}, p1 = {};
            p0 = __builtin_amdgcn_mfma_f32_16x16x32_bf16(a0, wpf, p0, 0, 0, 0);
            p1 = __builtin_amdgcn_mfma_f32_16x16x32_bf16(a1, wpf, p1, 0, 0, 0);
            for (int r = 0; r < 4; ++r) {
                int row0 = m0 + r0 + quad * 4 + r;
                ppart[((size_t)jb * 4096 + row0) * 16 + l16] = p0[r];
                ppart[((size_t)jb * 4096 + row0 + 16) * 16 + l16] = p1[r];
            }
        }

        gsync(bvars, bvars + 1);  // ppart + hout visible device-wide

        // phase 2: softmax head for 8 rows/block (threads 0..127)
        if (t < 128) {
            int row = bid * 8 + (t >> 4), n = t & 15;
            float p = pb;
            for (int q = 0; q < 16; ++q)
                p += ppart[((size_t)q * 4096 + row) * 16 + n];
            float vmax = (n == 15) ? -3.0e38f : p;
            for (int m = 1; m < 16; m <<= 1) vmax = fmaxf(vmax, __shfl_xor(vmax, m));
            float e = (n == 15) ? 0.f : __expf(p - vmax);
            float s = e;
            for (int m = 1; m < 16; m <<= 1) s += __shfl_xor(s, m);
            float res = (n == 15) ? sigm(p) : e / s;
            hout[(size_t)row * 544 + 512 + n] = (bf16)res;
            outp[(size_t)row * 512 + st * 16 + n] = res;
        }

        if (st != 31) gsync(bvars, bvars + 1);  // xt visible before next step
    }
}

// ---------------------------------------------------------------------------
extern "C" void kernel_launch(void* const* d_in, const int* in_sizes, int n_in,
                              void* d_out, int out_size, void* d_ws, size_t ws_size,
                              hipStream_t stream) {
    const float* xf   = (const float*)d_in[0];
    const float* W1f  = (const float*)d_in[1];  const float* b1  = (const float*)d_in[2];
    const float* W2f  = (const float*)d_in[3];  const float* b2  = (const float*)d_in[4];
    const float* W3f  = (const float*)d_in[5];  const float* b3  = (const float*)d_in[6];
    const float* Wh1f = (const float*)d_in[7];  const float* bh1 = (const float*)d_in[8];
    const float* Wh2f = (const float*)d_in[9];  const float* bh2 = (const float*)d_in[10];
    const float* Wc1f = (const float*)d_in[11]; const float* bc1 = (const float*)d_in[12];
    const float* Wc2f = (const float*)d_in[13]; const float* bc2 = (const float*)d_in[14];
    const float* Wx1f = (const float*)d_in[15]; const float* bx1 = (const float*)d_in[16];
    const float* Wx2f = (const float*)d_in[17]; const float* bx2 = (const float*)d_in[18];
    const float* Wihf = (const float*)d_in[19]; const float* bih = (const float*)d_in[20];
    const float* Whhf = (const float*)d_in[21]; const float* bhh = (const float*)d_in[22];
    const float* Wpf  = (const float*)d_in[23]; const float* bp  = (const float*)d_in[24];
    float* out = (float*)d_out;
    char* ws = (char*)d_ws;

    // layout (bytes): h1b/bufA 0..4456448 | bufB ..8650752 | h0b ..13107200 |
    // cb ..21495808 | Wcomb ..23724032 | cvt ..28606464 | bvars ..28606472
    bf16*  h1b  = (bf16*)(ws + 0);            // [4096,544]; early: z-buf (ldc 512)
    bf16*  bufA = h1b;                        //   alias — z3 dead before step 0
    bf16*  bufB = (bf16*)(ws + 4456448);      // [4096,512]; loop: ppart alias
    bf16*  h0b  = (bf16*)(ws + 8650752);      // [4096,544]
    float* cb   = (float*)(ws + 13107200);    // [4096,512] fp32
    bf16*  Wcb  = (bf16*)(ws + 21495808);     // [2048,544]
    bf16*  cvt  = (bf16*)(ws + 23724032);     // packed bf16 weights
    unsigned* bvars = (unsigned*)(ws + 28606464);  // grid-barrier cnt/gen
    float* ppart = (float*)bufB;              // [16,4096,16] f32 = 4 MB exact

    const unsigned Ns[11] = {
        4096u * 128u,  // x
        512u * 128u,   // W1
        512u * 512u, 512u * 512u, 512u * 512u, 512u * 512u,  // W2,W3,Wh1,Wh2
        512u * 512u, 512u * 512u, 512u * 512u,               // Wc1,Wc2,Wx1
        16u * 512u,    // Wx2
        16u * 512u     // Wp
    };
    const float* srcs[11] = { xf, W1f, W2f, W3f, Wh1f, Wh2f, Wc1f, Wc2f,
                              Wx1f, Wx2f, Wpf };
    Cvt11 ca;
    unsigned off[12]; off[0] = 0;
    for (int i = 0; i < 11; ++i) {
        ca.src[i] = srcs[i];
        ca.gcnt[i] = Ns[i] >> 3;
        off[i + 1] = off[i] + Ns[i];
    }
    unsigned total_g = off[11] >> 3;
    cvt_all<<<dim3((total_g + 255) / 256), dim3(256), 0, stream>>>(ca, cvt, total_g);
    pack_w<<<dim3(2048), dim3(128), 0, stream>>>(Whhf, Wihf, Wcb);

    const bf16* xb   = cvt + off[0];
    const bf16* W1b  = cvt + off[1];
    const bf16* W2b  = cvt + off[2];
    const bf16* W3b  = cvt + off[3];
    const bf16* Wh1b = cvt + off[4];
    const bf16* Wh2b = cvt + off[5];
    const bf16* Wc1b = cvt + off[6];
    const bf16* Wc2b = cvt + off[7];
    const bf16* Wx1b = cvt + off[8];
    const bf16* Wx2b = cvt + off[9];
    const bf16* Wpb  = cvt + off[10];

    dim3 blk(256);
    dim3 gg(4, 64);  // N/128 x M/64
    gemm_bt<1, bf16 ><<<gg, blk, 0, stream>>>(xb,   W1b,  b1,  bufA, 4096, 512, 128, 512);
    gemm_bt<1, bf16 ><<<gg, blk, 0, stream>>>(bufA, W2b,  b2,  bufB, 4096, 512, 512, 512);
    gemm_bt<1, bf16 ><<<gg, blk, 0, stream>>>(bufB, W3b,  b3,  bufA, 4096, 512, 512, 512);
    gemm_bt<1, bf16 ><<<gg, blk, 0, stream>>>(bufA, Wh1b, bh1, bufB, 4096, 512, 512, 512);
    gemm_bt<0, bf16 ><<<gg, blk, 0, stream>>>(bufB, Wh2b, bh2, h0b,  4096, 512, 512, 544);
    gemm_bt<1, bf16 ><<<gg, blk, 0, stream>>>(bufA, Wc1b, bc1, bufB, 4096, 512, 512, 512);
    gemm_bt<0, float><<<gg, blk, 0, stream>>>(bufB, Wc2b, bc2, cb,   4096, 512, 512, 512);
    gemm_bt<1, bf16 ><<<gg, blk, 0, stream>>>(bufA, Wx1b, bx1, bufB, 4096, 512, 512, 512);
    // bufA (=h1b) dead from here; zero pads + barrier words before loop
    zero_pad<<<dim3(64), blk, 0, stream>>>(h0b, h1b, bvars);
    head_mfma<<<dim3(64), blk, 0, stream>>>(bufB, 512, Wx2b, bx2,
                                            h0b + 512, 544, (float*)nullptr, 0);

    // one persistent kernel replaces 64 lstm_step/head_mfma launches
    lstm_loop<<<dim3(NBLK), blk, 0, stream>>>(Wcb, Wpb, bih, bhh, bp, cb,
                                              h0b, h1b, ppart, out, bvars);
}

// Round 2
// 1109.980 us; speedup vs baseline: 4.6395x; 4.6395x over previous
//
#include <hip/hip_runtime.h>
#include <hip/hip_bf16.h>

typedef __bf16 bf16;
typedef bf16 bf16x8 __attribute__((ext_vector_type(8)));
typedef float f32x4 __attribute__((ext_vector_type(4)));

__device__ __forceinline__ void glds16(const void* g, void* l) {
    __builtin_amdgcn_global_load_lds(
        (const __attribute__((address_space(1))) void*)g,
        (__attribute__((address_space(3))) void*)l, 16, 0, 0);
}

__device__ __forceinline__ float sigm(float x) { return 1.0f / (1.0f + __expf(-x)); }
__device__ __forceinline__ float tanh_f(float x) { return 2.0f / (1.0f + __expf(-2.0f * x)) - 1.0f; }

// ---------------------------------------------------------------------------
// fp32 -> bf16 conversion of x + 11 matrices into one packed ws area.
// ---------------------------------------------------------------------------
struct Cvt11 { const float* src[11]; unsigned gcnt[11]; };  // gcnt = elems/8

__global__ __launch_bounds__(256) void cvt_all(Cvt11 a, bf16* __restrict__ dst,
                                               unsigned total_g) {
    unsigned g = blockIdx.x * 256 + threadIdx.x;
    if (g >= total_g) return;
    unsigned s = 0, base = 0;
    while (g >= base + a.gcnt[s]) { base += a.gcnt[s]; ++s; }
    const float* sp = a.src[s] + (size_t)(g - base) * 8;
    float4 v0 = ((const float4*)sp)[0];
    float4 v1 = ((const float4*)sp)[1];
    bf16x8 o;
    o[0] = (bf16)v0.x; o[1] = (bf16)v0.y; o[2] = (bf16)v0.z; o[3] = (bf16)v0.w;
    o[4] = (bf16)v1.x; o[5] = (bf16)v1.y; o[6] = (bf16)v1.z; o[7] = (bf16)v1.w;
    *(bf16x8*)(dst + (size_t)g * 8) = o;
}

// Pack Wcomb[2048,544] = Whh[2048,512] || Wih[2048,16] || zeros[16], bf16.
__global__ __launch_bounds__(128) void pack_w(const float* __restrict__ Whh,
                                              const float* __restrict__ Wih,
                                              bf16* __restrict__ Wc) {
    int row = blockIdx.x, seg = threadIdx.x;
    if (seg >= 68) return;
    bf16x8 o = {};
    if (seg < 64) {
        const float* sp = Whh + (size_t)row * 512 + seg * 8;
        float4 v0 = ((const float4*)sp)[0];
        float4 v1 = ((const float4*)sp)[1];
        o[0]=(bf16)v0.x; o[1]=(bf16)v0.y; o[2]=(bf16)v0.z; o[3]=(bf16)v0.w;
        o[4]=(bf16)v1.x; o[5]=(bf16)v1.y; o[6]=(bf16)v1.z; o[7]=(bf16)v1.w;
    } else if (seg < 66) {
        const float* sp = Wih + (size_t)row * 16 + (seg - 64) * 8;
        float4 v0 = ((const float4*)sp)[0];
        float4 v1 = ((const float4*)sp)[1];
        o[0]=(bf16)v0.x; o[1]=(bf16)v0.y; o[2]=(bf16)v0.z; o[3]=(bf16)v0.w;
        o[4]=(bf16)v1.x; o[5]=(bf16)v1.y; o[6]=(bf16)v1.z; o[7]=(bf16)v1.w;
    }
    *(bf16x8*)(Wc + (size_t)row * 544 + seg * 8) = o;
}

// Zero pad cols 528..543 of both h buffers.
__global__ __launch_bounds__(256) void zero_pad(bf16* __restrict__ h0,
                                                bf16* __restrict__ h1) {
    int g = blockIdx.x * 256 + threadIdx.x;  // 4096*2*2 = 16384
    int row = g >> 2, b = (g >> 1) & 1, half = g & 1;
    bf16* p = (b ? h1 : h0) + (size_t)row * 544 + 528 + half * 8;
    *(bf16x8*)p = (bf16x8){};
}

// ---------------------------------------------------------------------------
// GEMM: C[M,N](ldc) = act(A[M,K] @ W[N,K]^T + bias).  BM=64, BN=128, BK=32.
// ---------------------------------------------------------------------------
template <int ACT, typename OutT>
__global__ __launch_bounds__(256) void gemm_bt(
    const bf16* __restrict__ A, const bf16* __restrict__ W,
    const float* __restrict__ bias, OutT* __restrict__ C,
    int M, int N, int K, int ldc)
{
    __shared__ __attribute__((aligned(16))) bf16 sA[64 * 32];   // 4 KB
    __shared__ __attribute__((aligned(16))) bf16 sB[128 * 32];  // 8 KB
    const int t = threadIdx.x;
    const int lane = t & 63, w = t >> 6;
    const int wm = w >> 1, wn = w & 1;
    const int quad = lane >> 4, l16 = lane & 15;
    const int m0 = blockIdx.y * 64, n0 = blockIdx.x * 128;

    f32x4 acc[2][4] = {};

    const int nk = K >> 5;
    for (int kc = 0; kc < nk; ++kc) {
        const int k0 = kc << 5;
        if (kc) __syncthreads();
        {   // A: 64x32 = 4 KB
            int row = t >> 2, kof = (t & 3) << 3;
            glds16(A + (size_t)(m0 + row) * K + k0 + kof, (char*)sA + (w << 10));
        }
        for (int i = 0; i < 2; ++i) {  // B: 128x32 = 8 KB
            int gi = (i << 8) + t;
            int row = gi >> 2, kof = (gi & 3) << 3;
            glds16(W + (size_t)(n0 + row) * K + k0 + kof,
                   (char*)sB + (i << 12) + (w << 10));
        }
        __syncthreads();
        bf16x8 af[2], bfr[4];
        for (int mi = 0; mi < 2; ++mi)
            af[mi] = *(const bf16x8*)(sA + ((wm * 32 + mi * 16 + l16) * 32 + quad * 8));
        for (int ni = 0; ni < 4; ++ni)
            bfr[ni] = *(const bf16x8*)(sB + ((wn * 64 + ni * 16 + l16) * 32 + quad * 8));
        for (int mi = 0; mi < 2; ++mi)
            for (int ni = 0; ni < 4; ++ni)
                acc[mi][ni] = __builtin_amdgcn_mfma_f32_16x16x32_bf16(
                    af[mi], bfr[ni], acc[mi][ni], 0, 0, 0);
    }
    for (int mi = 0; mi < 2; ++mi) {
        for (int ni = 0; ni < 4; ++ni) {
            int gn = n0 + wn * 64 + ni * 16 + l16;
            float bv = bias[gn];
            for (int r = 0; r < 4; ++r) {
                int gm = m0 + wm * 32 + mi * 16 + quad * 4 + r;
                float v = acc[mi][ni][r] + bv;
                if (ACT) v = v >= 0.f ? v : 0.2f * v;
                C[(size_t)gm * ldc + gn] = (OutT)v;
            }
        }
    }
}

// ---------------------------------------------------------------------------
// MFMA head (used once, for x0): p = A[:,0:512](lda) @ Wp[16,512]^T + b.
// Writes softmax/sigmoid result into h0b cols 512..527.
// ---------------------------------------------------------------------------
__global__ __launch_bounds__(256) void head_mfma(
    const bf16* __restrict__ A, int lda,
    const bf16* __restrict__ Wp16,
    const float* __restrict__ bias,
    bf16* __restrict__ xt_dst, int ldx)
{
    const int t = threadIdx.x;
    const int lane = t & 63, w = t >> 6;
    const int quad = lane >> 4, l16 = lane & 15;
    const int r0 = blockIdx.x * 64 + w * 16;
    f32x4 acc = {};
    for (int kk = 0; kk < 16; ++kk) {
        bf16x8 a = *(const bf16x8*)(A + (size_t)(r0 + l16) * lda + kk * 32 + quad * 8);
        bf16x8 b = *(const bf16x8*)(Wp16 + (size_t)l16 * 512 + kk * 32 + quad * 8);
        acc = __builtin_amdgcn_mfma_f32_16x16x32_bf16(a, b, acc, 0, 0, 0);
    }
    const int n = l16;
    const float bv = bias[n];
    for (int r = 0; r < 4; ++r) {
        float p = acc[r] + bv;
        float vmax = (n == 15) ? -3.0e38f : p;
        for (int m = 1; m < 16; m <<= 1) vmax = fmaxf(vmax, __shfl_xor(vmax, m));
        float e = (n == 15) ? 0.f : __expf(p - vmax);
        float s = e;
        for (int m = 1; m < 16; m <<= 1) s += __shfl_xor(s, m);
        float res = (n == 15) ? sigm(p) : e / s;
        int gr = r0 + quad * 4 + r;
        xt_dst[(size_t)gr * ldx + n] = (bf16)res;
    }
}

// ---------------------------------------------------------------------------
// Fused LSTM step, one launch per step.
// Block (jb=blockIdx.x 0..15, mb=blockIdx.y 0..31): rows mb*128..+127,
// units jb*32..+31, all 4 gates.
// K = 544 split as 8 phases of BK=64 (h cols 0..511, two [128][32] LDS
// planes per tile) + 1 xt phase (K=32: xt||zeros from LDS xA).
// Prologue (t>=1): reduce ppin partials -> softmax -> xA (+ write out[t-1]).
// Tail: h tile -> sA bounce -> 2 head MFMAs -> ppout partials.
// ---------------------------------------------------------------------------
template <int XT_FROM_PP>
__global__ __launch_bounds__(256) void lstm_step_f(
    const bf16* __restrict__ hin,   // [4096,544] (t=0: cols 512..543 = x0||0)
    bf16* __restrict__ hout,        // [4096,544], cols 0..511 written
    const bf16* __restrict__ Wc,    // [2048,544]
    const bf16* __restrict__ Wp16,  // [16,512]
    const float* __restrict__ bih, const float* __restrict__ bhh,
    const float* __restrict__ bp,
    float* __restrict__ cbuf,       // [4096,512] fp32
    const float* __restrict__ ppin, // [16][4096][16] (t>=1)
    float* __restrict__ ppout,      // [16][4096][16]
    float* __restrict__ outprev)    // out + (t-1)*16, row stride 512 (t>=1)
{
    __shared__ __attribute__((aligned(16))) bf16 sA[2 * 128 * 32];  // 16 KB, 2 K-planes
    __shared__ __attribute__((aligned(16))) bf16 sB[2 * 128 * 32];  // 16 KB
    __shared__ __attribute__((aligned(16))) bf16 xA[128 * 32];      // 8 KB
    const int t = threadIdx.x;
    const int lane = t & 63, w = t >> 6;
    const int wm = w >> 1, wn = w & 1;
    const int quad = lane >> 4, l16 = lane & 15;
    const int jb = blockIdx.x, mb = blockIdx.y;
    const int m0 = mb * 128, j0 = jb * 32;

    // stage A/B tiles for K-chunk kc (64 cols as two [128][32] planes)
    auto stageAB = [&](int kc) {
        const int k0 = kc << 6;
        for (int i = 0; i < 4; ++i) {
            int g = (i << 8) + t;
            int p = g >> 9, row = (g >> 2) & 127, ch = g & 3;
            glds16(hin + (size_t)(m0 + row) * 544 + k0 + p * 32 + ch * 8,
                   (char*)sA + (i << 12) + (w << 10));
        }
        for (int i = 0; i < 4; ++i) {
            int g = (i << 8) + t;
            int p = g >> 9, row = (g >> 2) & 127, ch = g & 3;
            int wr = ((row >> 5) << 9) + j0 + (row & 31);  // gate*512 + unit
            glds16(Wc + (size_t)wr * 544 + k0 + p * 32 + ch * 8,
                   (char*)sB + (i << 12) + (w << 10));
        }
    };
    // stage B tile for the xt phase (Wc cols 512..543) into sB plane 0
    auto stageBxt = [&]() {
        for (int i = 0; i < 2; ++i) {
            int g = (i << 8) + t;
            int row = g >> 2, ch = g & 3;
            int wr = ((row >> 5) << 9) + j0 + (row & 31);
            glds16(Wc + (size_t)wr * 544 + 512 + ch * 8,
                   (char*)sB + (i << 12) + (w << 10));
        }
    };

    stageAB(0);  // issue phase-0 loads first; xA work hides under them

    if (XT_FROM_PP) {
        // reduce 16 partials -> softmax head -> xA (one thread per row)
        if (t < 128) {
            const int row = m0 + t;
            float p[16];
#pragma unroll
            for (int n = 0; n < 16; ++n) p[n] = bp[n];
            for (int q = 0; q < 16; ++q) {
                const float4* pp = (const float4*)(ppin + ((size_t)(q << 12) + row) * 16);
                float4 v0 = pp[0], v1 = pp[1], v2 = pp[2], v3 = pp[3];
                p[0]+=v0.x; p[1]+=v0.y; p[2]+=v0.z; p[3]+=v0.w;
                p[4]+=v1.x; p[5]+=v1.y; p[6]+=v1.z; p[7]+=v1.w;
                p[8]+=v2.x; p[9]+=v2.y; p[10]+=v2.z; p[11]+=v2.w;
                p[12]+=v3.x; p[13]+=v3.y; p[14]+=v3.z; p[15]+=v3.w;
            }
            float vmax = p[0];
#pragma unroll
            for (int n = 1; n < 15; ++n) vmax = fmaxf(vmax, p[n]);
            float e[15], s = 0.f;
#pragma unroll
            for (int n = 0; n < 15; ++n) { e[n] = __expf(p[n] - vmax); s += e[n]; }
            float inv = 1.0f / s;
            float lastv = sigm(p[15]);
            bf16* xr = xA + t * 32;
#pragma unroll
            for (int n = 0; n < 15; ++n) xr[n] = (bf16)(e[n] * inv);
            xr[15] = (bf16)lastv;
            *(bf16x8*)(xr + 16) = (bf16x8){};
            *(bf16x8*)(xr + 24) = (bf16x8){};
            if (jb == 0) {  // write ys[t-1] once
                float* op = outprev + (size_t)row * 512;
#pragma unroll
                for (int n = 0; n < 15; ++n) op[n] = e[n] * inv;
                op[15] = lastv;
            }
        }
    } else {
        // t=0: xt tile comes from hin cols 512..543 (head_mfma + zero_pad)
        for (int i = 0; i < 2; ++i) {
            int g = (i << 8) + t;
            int row = g >> 2, ch = g & 3;
            glds16(hin + (size_t)(m0 + row) * 544 + 512 + ch * 8,
                   (char*)xA + (i << 12) + (w << 10));
        }
    }
    __syncthreads();

    f32x4 acc[4][4] = {};  // [mi][gate]
    for (int kc = 0; kc < 9; ++kc) {
        if (kc < 8) {
            for (int ks = 0; ks < 2; ++ks) {
                bf16x8 af[4], bfr[4];
                for (int mi = 0; mi < 4; ++mi)
                    af[mi] = *(const bf16x8*)(sA + ks * 4096 +
                                              (wm * 64 + mi * 16 + l16) * 32 + quad * 8);
                for (int g2 = 0; g2 < 4; ++g2)
                    bfr[g2] = *(const bf16x8*)(sB + ks * 4096 +
                                               (g2 * 32 + wn * 16 + l16) * 32 + quad * 8);
                for (int mi = 0; mi < 4; ++mi)
                    for (int g2 = 0; g2 < 4; ++g2)
                        acc[mi][g2] = __builtin_amdgcn_mfma_f32_16x16x32_bf16(
                            af[mi], bfr[g2], acc[mi][g2], 0, 0, 0);
            }
            __syncthreads();                     // done reading sA/sB
            if (kc < 7) stageAB(kc + 1); else stageBxt();
            __syncthreads();                     // staged (vmcnt drained)
        } else {
            bf16x8 af[4], bfr[4];
            for (int mi = 0; mi < 4; ++mi)
                af[mi] = *(const bf16x8*)(xA + (wm * 64 + mi * 16 + l16) * 32 + quad * 8);
            for (int g2 = 0; g2 < 4; ++g2)
                bfr[g2] = *(const bf16x8*)(sB + (g2 * 32 + wn * 16 + l16) * 32 + quad * 8);
            for (int mi = 0; mi < 4; ++mi)
                for (int g2 = 0; g2 < 4; ++g2)
                    acc[mi][g2] = __builtin_amdgcn_mfma_f32_16x16x32_bf16(
                        af[mi], bfr[g2], acc[mi][g2], 0, 0, 0);
        }
    }

    // epilogue: gates, c update (fp32 global), h write + sA bounce
    const int j = j0 + wn * 16 + l16;
    float bsum[4];
    for (int g2 = 0; g2 < 4; ++g2)
        bsum[g2] = bih[(g2 << 9) + j] + bhh[(g2 << 9) + j];
    for (int mi = 0; mi < 4; ++mi) {
        for (int r = 0; r < 4; ++r) {
            int lr = wm * 64 + mi * 16 + quad * 4 + r;
            int gm = m0 + lr;
            float i_ = sigm(acc[mi][0][r] + bsum[0]);
            float f_ = sigm(acc[mi][1][r] + bsum[1]);
            float g_ = tanh_f(acc[mi][2][r] + bsum[2]);
            float o_ = sigm(acc[mi][3][r] + bsum[3]);
            float cn = f_ * cbuf[(size_t)gm * 512 + j] + i_ * g_;
            cbuf[(size_t)gm * 512 + j] = cn;
            float hv = o_ * tanh_f(cn);
            bf16 hb = (bf16)hv;
            hout[(size_t)gm * 544 + j] = hb;
            sA[lr * 32 + wn * 16 + l16] = hb;  // h tile bounce, [128][32]
        }
    }
    __syncthreads();

    // head partial: ppout[jb][rows][16] = h_tile @ Wp[:, j0:j0+32]^T
    {
        const bf16x8 wpf = *(const bf16x8*)(Wp16 + (size_t)l16 * 512 + j0 + quad * 8);
        const int r0h = w * 32;
        bf16x8 a0 = *(const bf16x8*)(sA + (r0h + l16) * 32 + quad * 8);
        bf16x8 a1 = *(const bf16x8*)(sA + (r0h + 16 + l16) * 32 + quad * 8);
        f32x4 p0 = {}, p1 = {};
        p0 = __builtin_amdgcn_mfma_f32_16x16x32_bf16(a0, wpf, p0, 0, 0, 0);
        p1 = __builtin_amdgcn_mfma_f32_16x16x32_bf16(a1, wpf, p1, 0, 0, 0);
        for (int r = 0; r < 4; ++r) {
            int row0 = m0 + r0h + quad * 4 + r;
            ppout[((size_t)jb * 4096 + row0) * 16 + l16] = p0[r];
            ppout[((size_t)jb * 4096 + row0 + 16) * 16 + l16] = p1[r];
        }
    }
}

// Final softmax head for ys[31] from ppart.
__global__ __launch_bounds__(256) void head_final(const float* __restrict__ ppin,
                                                  const float* __restrict__ bp,
                                                  float* __restrict__ outp) {
    const int t = threadIdx.x;
    if (t >= 128) return;
    const int row = blockIdx.x * 128 + t;
    float p[16];
#pragma unroll
    for (int n = 0; n < 16; ++n) p[n] = bp[n];
    for (int q = 0; q < 16; ++q) {
        const float4* pp = (const float4*)(ppin + ((size_t)(q << 12) + row) * 16);
        float4 v0 = pp[0], v1 = pp[1], v2 = pp[2], v3 = pp[3];
        p[0]+=v0.x; p[1]+=v0.y; p[2]+=v0.z; p[3]+=v0.w;
        p[4]+=v1.x; p[5]+=v1.y; p[6]+=v1.z; p[7]+=v1.w;
        p[8]+=v2.x; p[9]+=v2.y; p[10]+=v2.z; p[11]+=v2.w;
        p[12]+=v3.x; p[13]+=v3.y; p[14]+=v3.z; p[15]+=v3.w;
    }
    float vmax = p[0];
#pragma unroll
    for (int n = 1; n < 15; ++n) vmax = fmaxf(vmax, p[n]);
    float e[15], s = 0.f;
#pragma unroll
    for (int n = 0; n < 15; ++n) { e[n] = __expf(p[n] - vmax); s += e[n]; }
    float inv = 1.0f / s;
    float* op = outp + (size_t)row * 512;
#pragma unroll
    for (int n = 0; n < 15; ++n) op[n] = e[n] * inv;
    op[15] = sigm(p[15]);
}

// ---------------------------------------------------------------------------
extern "C" void kernel_launch(void* const* d_in, const int* in_sizes, int n_in,
                              void* d_out, int out_size, void* d_ws, size_t ws_size,
                              hipStream_t stream) {
    const float* xf   = (const float*)d_in[0];
    const float* W1f  = (const float*)d_in[1];  const float* b1  = (const float*)d_in[2];
    const float* W2f  = (const float*)d_in[3];  const float* b2  = (const float*)d_in[4];
    const float* W3f  = (const float*)d_in[5];  const float* b3  = (const float*)d_in[6];
    const float* Wh1f = (const float*)d_in[7];  const float* bh1 = (const float*)d_in[8];
    const float* Wh2f = (const float*)d_in[9];  const float* bh2 = (const float*)d_in[10];
    const float* Wc1f = (const float*)d_in[11]; const float* bc1 = (const float*)d_in[12];
    const float* Wc2f = (const float*)d_in[13]; const float* bc2 = (const float*)d_in[14];
    const float* Wx1f = (const float*)d_in[15]; const float* bx1 = (const float*)d_in[16];
    const float* Wx2f = (const float*)d_in[17]; const float* bx2 = (const float*)d_in[18];
    const float* Wihf = (const float*)d_in[19]; const float* bih = (const float*)d_in[20];
    const float* Whhf = (const float*)d_in[21]; const float* bhh = (const float*)d_in[22];
    const float* Wpf  = (const float*)d_in[23]; const float* bp  = (const float*)d_in[24];
    float* out = (float*)d_out;
    char* ws = (char*)d_ws;

    // layout (bytes): h1b/bufA 0..4456448 | bufB ..8650752 | h0b ..13107200 |
    // cb ..21495808 | Wcomb ..23724032 | cvt ..28606464
    bf16*  h1b  = (bf16*)(ws + 0);            // [4096,544]; early: z-buf (ldc 512)
    bf16*  bufA = h1b;                        //   alias — z3 dead before step 0
    bf16*  bufB = (bf16*)(ws + 4456448);      // [4096,512]; loop: ppart P0
    bf16*  h0b  = (bf16*)(ws + 8650752);      // [4096,544]
    float* cb   = (float*)(ws + 13107200);    // [4096,512] fp32
    bf16*  Wcb  = (bf16*)(ws + 21495808);     // [2048,544]
    bf16*  cvt  = (bf16*)(ws + 23724032);     // packed bf16 weights

    const unsigned Ns[11] = {
        4096u * 128u,  // x
        512u * 128u,   // W1
        512u * 512u, 512u * 512u, 512u * 512u, 512u * 512u,  // W2,W3,Wh1,Wh2
        512u * 512u, 512u * 512u, 512u * 512u,               // Wc1,Wc2,Wx1
        16u * 512u,    // Wx2
        16u * 512u     // Wp
    };
    const float* srcs[11] = { xf, W1f, W2f, W3f, Wh1f, Wh2f, Wc1f, Wc2f,
                              Wx1f, Wx2f, Wpf };
    Cvt11 ca;
    unsigned off[12]; off[0] = 0;
    for (int i = 0; i < 11; ++i) {
        ca.src[i] = srcs[i];
        ca.gcnt[i] = Ns[i] >> 3;
        off[i + 1] = off[i] + Ns[i];
    }
    unsigned total_g = off[11] >> 3;
    cvt_all<<<dim3((total_g + 255) / 256), dim3(256), 0, stream>>>(ca, cvt, total_g);
    pack_w<<<dim3(2048), dim3(128), 0, stream>>>(Whhf, Wihf, Wcb);

    const bf16* xb   = cvt + off[0];
    const bf16* W1b  = cvt + off[1];
    const bf16* W2b  = cvt + off[2];
    const bf16* W3b  = cvt + off[3];
    const bf16* Wh1b = cvt + off[4];
    const bf16* Wh2b = cvt + off[5];
    const bf16* Wc1b = cvt + off[6];
    const bf16* Wc2b = cvt + off[7];
    const bf16* Wx1b = cvt + off[8];
    const bf16* Wx2b = cvt + off[9];
    const bf16* Wpb  = cvt + off[10];

    // ppart double buffers (intra-kernel read/write race otherwise):
    // P0 = bufB (dead after head_mfma), P1 = first 4 MB of cvt area
    // (x|W1|W2..Wx1 — all dead once the prologue GEMMs + head_mfma ran;
    //  Wx2b/Wpb live at byte offsets >= 4.62 MB, safely past P1's 4 MB).
    float* P0 = (float*)bufB;
    float* P1 = (float*)cvt;

    dim3 blk(256);
    dim3 gg(4, 64);  // N/128 x M/64
    gemm_bt<1, bf16 ><<<gg, blk, 0, stream>>>(xb,   W1b,  b1,  bufA, 4096, 512, 128, 512);
    gemm_bt<1, bf16 ><<<gg, blk, 0, stream>>>(bufA, W2b,  b2,  bufB, 4096, 512, 512, 512);
    gemm_bt<1, bf16 ><<<gg, blk, 0, stream>>>(bufB, W3b,  b3,  bufA, 4096, 512, 512, 512);
    gemm_bt<1, bf16 ><<<gg, blk, 0, stream>>>(bufA, Wh1b, bh1, bufB, 4096, 512, 512, 512);
    gemm_bt<0, bf16 ><<<gg, blk, 0, stream>>>(bufB, Wh2b, bh2, h0b,  4096, 512, 512, 544);
    gemm_bt<1, bf16 ><<<gg, blk, 0, stream>>>(bufA, Wc1b, bc1, bufB, 4096, 512, 512, 512);
    gemm_bt<0, float><<<gg, blk, 0, stream>>>(bufB, Wc2b, bc2, cb,   4096, 512, 512, 512);
    gemm_bt<1, bf16 ><<<gg, blk, 0, stream>>>(bufA, Wx1b, bx1, bufB, 4096, 512, 512, 512);
    // bufA (=h1b) dead from here; zero pads before any h-buffer use
    zero_pad<<<dim3(64), blk, 0, stream>>>(h0b, h1b);
    head_mfma<<<dim3(64), blk, 0, stream>>>(bufB, 512, Wx2b, bx2, h0b + 512, 544);

    bf16* hb[2] = { h0b, h1b };
    for (int st = 0; st < 32; ++st) {
        const bf16* hp = hb[st & 1];
        bf16* hn = hb[(st + 1) & 1];
        if (st == 0) {
            lstm_step_f<0><<<dim3(16, 32), blk, 0, stream>>>(
                hp, hn, Wcb, Wpb, bih, bhh, bp, cb,
                (const float*)nullptr, P1, (float*)nullptr);
        } else {
            float* ppin  = (st & 1) ? P1 : P0;   // written by step st-1
            float* ppout = (st & 1) ? P0 : P1;
            lstm_step_f<1><<<dim3(16, 32), blk, 0, stream>>>(
                hp, hn, Wcb, Wpb, bih, bhh, bp, cb,
                ppin, ppout, out + (size_t)(st - 1) * 16);
        }
    }
    // step 31 (odd) wrote P0
    head_final<<<dim3(32), blk, 0, stream>>>(P0, bp, out + (size_t)31 * 16);
}